// Round 15
// baseline (53.720 us; speedup 1.0000x reference)
//
#include <hip/hip_runtime.h>
#include <math.h>

#define BB 64
#define HH 512
#define IN_DIM 256
#define OUT_DIM 256

typedef float f4 __attribute__((ext_vector_type(4)));

__device__ __forceinline__ float fast_tanh(float x) {
    const float ax = fabsf(x);
    const float e  = __expf(2.f * ax);
    const float t  = 1.f - 2.f / (e + 1.f);
    return copysignf(t, x);
}

__device__ __forceinline__ f4 clamp1(f4 v) {
    return __builtin_elementwise_min(__builtin_elementwise_max(v, (f4)(-1.f)), (f4)(1.f));
}

// One wave handles FOUR rows (b, i0..i0+3) of hebb.
// i-slow / b-fast logical order + bijective XCD swizzle (grid 2048 = 8*256):
// XCD k executes logical blocks [256k, 256k+256) = 4 complete row-slabs, so
// each w/alpha slab is fetched into exactly one XCD's L2.
// __launch_bounds__(256, 8): cap VGPR at 64 -> 8 blocks/CU resident
// (32 waves/CU) for maximum in-flight memory per CU.
__global__ __launch_bounds__(256, 8) void fused_row_kernel(
    const float* __restrict__ inputs, const float* __restrict__ prev,
    const float* __restrict__ hebb,   const float* __restrict__ w,
    const float* __restrict__ alpha,  const float* __restrict__ eta,
    const float* __restrict__ Wi,     const float* __restrict__ bi,
    float* __restrict__ hidden, float* __restrict__ hebb_new)
{
    const int h   = blockIdx.x;
    const int cpx = gridDim.x >> 3;            // 256
    const int L   = (h & 7) * cpx + (h >> 3);  // bijective XCD swizzle

    const int wid4 = (L * 256 + (int)threadIdx.x) >> 6;  // [0, H/4*B)
    const int lane = threadIdx.x & 63;
    const int b  = wid4 & (BB - 1);      // batch fast
    const int i0 = (wid4 >> 6) * 4;      // row quad slow

    const int j0 = lane * 4;
    const int j1 = j0 + 256;

    const float* prow = prev + (size_t)b * HH;
    const f4 p0 = *(const f4*)(prow + j0);
    const f4 p1 = *(const f4*)(prow + j1);
    const f4 xv = *(const f4*)(inputs + (size_t)b * IN_DIM + j0);

    const size_t rbase = ((size_t)b * HH + i0) * HH;

    f4 h0[4], h1[4];
    #pragma unroll
    for (int r = 0; r < 4; ++r) {
        h0[r] = *(const f4*)(hebb + rbase + (size_t)r * HH + j0);
        h1[r] = *(const f4*)(hebb + rbase + (size_t)r * HH + j1);
    }

    float acc[4];
    #pragma unroll
    for (int r = 0; r < 4; ++r) {
        const size_t wo = (size_t)(i0 + r) * HH;
        const f4 w0 = *(const f4*)(w + wo + j0);
        const f4 w1 = *(const f4*)(w + wo + j1);
        const f4 a0 = *(const f4*)(alpha + wo + j0);
        const f4 a1 = *(const f4*)(alpha + wo + j1);
        f4 v = (w0 + a0 * h0[r]) * p0 + (w1 + a1 * h1[r]) * p1;
        const f4 wi = *(const f4*)(Wi + (size_t)(i0 + r) * IN_DIM + j0);
        v += wi * xv;
        acc[r] = v.x + v.y + v.z + v.w;
    }

    #pragma unroll
    for (int d = 32; d > 0; d >>= 1) {
        acc[0] += __shfl_xor(acc[0], d, 64);
        acc[1] += __shfl_xor(acc[1], d, 64);
        acc[2] += __shfl_xor(acc[2], d, 64);
        acc[3] += __shfl_xor(acc[3], d, 64);
    }

    const float et = eta[0];
    const float hv0 = fast_tanh(acc[0] + bi[i0]);
    const float hv1 = fast_tanh(acc[1] + bi[i0 + 1]);
    const float hv2 = fast_tanh(acc[2] + bi[i0 + 2]);
    const float hv3 = fast_tanh(acc[3] + bi[i0 + 3]);

    if (lane == 0) {
        f4 hvv; hvv.x = hv0; hvv.y = hv1; hvv.z = hv2; hvv.w = hv3;
        *(f4*)(hidden + (size_t)b * HH + i0) = hvv;   // i0 % 4 == 0 -> aligned
    }

    const float e0 = et * hv0, e1 = et * hv1, e2 = et * hv2, e3 = et * hv3;

    *(f4*)(hebb_new + rbase + 0 * HH + j0) = clamp1(h0[0] + e0 * p0);
    *(f4*)(hebb_new + rbase + 0 * HH + j1) = clamp1(h1[0] + e0 * p1);
    *(f4*)(hebb_new + rbase + 1 * HH + j0) = clamp1(h0[1] + e1 * p0);
    *(f4*)(hebb_new + rbase + 1 * HH + j1) = clamp1(h1[1] + e1 * p1);
    *(f4*)(hebb_new + rbase + 2 * HH + j0) = clamp1(h0[2] + e2 * p0);
    *(f4*)(hebb_new + rbase + 2 * HH + j1) = clamp1(h1[2] + e2 * p1);
    *(f4*)(hebb_new + rbase + 3 * HH + j0) = clamp1(h0[3] + e3 * p0);
    *(f4*)(hebb_new + rbase + 3 * HH + j1) = clamp1(h1[3] + e3 * p1);
}

// One wave per output element: o in [0,256) -> a_out[b,o]; o==256 -> v_out[b].
__global__ __launch_bounds__(256) void out_proj_kernel(
    const float* __restrict__ hidden, const float* __restrict__ Wo,
    const float* __restrict__ bo,     const float* __restrict__ Wv,
    const float* __restrict__ bv,
    float* __restrict__ a_out, float* __restrict__ v_out)
{
    const int wid  = (blockIdx.x * 256 + threadIdx.x) >> 6;  // [0, 64*257)
    const int lane = threadIdx.x & 63;
    const int b = wid / 257;
    const int o = wid - b * 257;

    const int j0 = lane * 4;
    const int j1 = j0 + 256;

    const float* hrow = hidden + (size_t)b * HH;
    const f4 h0 = *(const f4*)(hrow + j0);
    const f4 h1 = *(const f4*)(hrow + j1);

    const float* wrow = (o < OUT_DIM) ? (Wo + (size_t)o * HH) : Wv;
    const f4 w0 = *(const f4*)(wrow + j0);
    const f4 w1 = *(const f4*)(wrow + j1);

    const f4 pv = h0 * w0 + h1 * w1;
    float acc = pv.x + pv.y + pv.z + pv.w;

    #pragma unroll
    for (int d = 32; d > 0; d >>= 1) acc += __shfl_xor(acc, d, 64);

    if (lane == 0) {
        if (o < OUT_DIM) a_out[(size_t)b * OUT_DIM + o] = acc + bo[o];
        else             v_out[b] = acc + bv[0];
    }
}

extern "C" void kernel_launch(void* const* d_in, const int* in_sizes, int n_in,
                              void* d_out, int out_size, void* d_ws, size_t ws_size,
                              hipStream_t stream) {
    const float* inputs = (const float*)d_in[0];
    const float* prev   = (const float*)d_in[1];
    const float* hebb   = (const float*)d_in[2];
    const float* w      = (const float*)d_in[3];
    const float* alpha  = (const float*)d_in[4];
    const float* eta    = (const float*)d_in[5];
    const float* Wi     = (const float*)d_in[6];
    const float* bi     = (const float*)d_in[7];
    const float* Wo     = (const float*)d_in[8];
    const float* bo     = (const float*)d_in[9];
    const float* Wv     = (const float*)d_in[10];
    const float* bv     = (const float*)d_in[11];

    float* out      = (float*)d_out;
    float* a_out    = out;                       // [B, OUT]
    float* v_out    = a_out + BB * OUT_DIM;      // [B, 1]
    float* hidden   = v_out + BB;                // [B, H]
    float* hebb_new = hidden + BB * HH;          // [B, H, H]

    // H/4 * B = 8192 waves, 4 per block -> 2048 blocks (multiple of 8)
    fused_row_kernel<<<dim3(HH / 4 * BB / 4), dim3(256), 0, stream>>>(
        inputs, prev, hebb, w, alpha, eta, Wi, bi, hidden, hebb_new);

    out_proj_kernel<<<dim3((BB * 257 + 3) / 4), dim3(256), 0, stream>>>(
        hidden, Wo, bo, Wv, bv, a_out, v_out);
}

// Round 16
// 41.837 us; speedup vs baseline: 1.2840x; 1.2840x over previous
//
#include <hip/hip_runtime.h>
#include <math.h>

#define BB 64
#define HH 512
#define IN_DIM 256
#define OUT_DIM 256

typedef float f4 __attribute__((ext_vector_type(4)));

__device__ __forceinline__ float fast_tanh(float x) {
    const float ax = fabsf(x);
    const float e  = __expf(2.f * ax);
    const float t  = 1.f - 2.f / (e + 1.f);
    return copysignf(t, x);
}

__device__ __forceinline__ f4 clamp1(f4 v) {
    return __builtin_elementwise_min(__builtin_elementwise_max(v, (f4)(-1.f)), (f4)(1.f));
}

// One wave handles FOUR rows (b, i0..i0+3) of hebb.
// i-slow / b-fast logical order + bijective XCD swizzle (grid 2048 = 8*256).
// __launch_bounds__(256, 6): 6 blocks/CU (24 waves/CU), VGPR cap ~85 so the
// ~52-VGPR body is untouched (R15 showed a <=64 cap collapses it to 32+spill).
__global__ __launch_bounds__(256, 6) void fused_row_kernel(
    const float* __restrict__ inputs, const float* __restrict__ prev,
    const float* __restrict__ hebb,   const float* __restrict__ w,
    const float* __restrict__ alpha,  const float* __restrict__ eta,
    const float* __restrict__ Wi,     const float* __restrict__ bi,
    float* __restrict__ hidden, float* __restrict__ hebb_new)
{
    const int h   = blockIdx.x;
    const int cpx = gridDim.x >> 3;            // 256
    const int L   = (h & 7) * cpx + (h >> 3);  // bijective XCD swizzle

    const int wid4 = (L * 256 + (int)threadIdx.x) >> 6;  // [0, H/4*B)
    const int lane = threadIdx.x & 63;
    const int b  = wid4 & (BB - 1);      // batch fast
    const int i0 = (wid4 >> 6) * 4;      // row quad slow

    const int j0 = lane * 4;
    const int j1 = j0 + 256;

    const float* prow = prev + (size_t)b * HH;
    const f4 p0 = *(const f4*)(prow + j0);
    const f4 p1 = *(const f4*)(prow + j1);
    const f4 xv = *(const f4*)(inputs + (size_t)b * IN_DIM + j0);

    const size_t rbase = ((size_t)b * HH + i0) * HH;

    f4 h0[4], h1[4];
    #pragma unroll
    for (int r = 0; r < 4; ++r) {
        h0[r] = *(const f4*)(hebb + rbase + (size_t)r * HH + j0);
        h1[r] = *(const f4*)(hebb + rbase + (size_t)r * HH + j1);
    }

    float acc[4];
    #pragma unroll
    for (int r = 0; r < 4; ++r) {
        const size_t wo = (size_t)(i0 + r) * HH;
        const f4 w0 = *(const f4*)(w + wo + j0);
        const f4 w1 = *(const f4*)(w + wo + j1);
        const f4 a0 = *(const f4*)(alpha + wo + j0);
        const f4 a1 = *(const f4*)(alpha + wo + j1);
        f4 v = (w0 + a0 * h0[r]) * p0 + (w1 + a1 * h1[r]) * p1;
        const f4 wi = *(const f4*)(Wi + (size_t)(i0 + r) * IN_DIM + j0);
        v += wi * xv;
        acc[r] = v.x + v.y + v.z + v.w;
    }

    #pragma unroll
    for (int d = 32; d > 0; d >>= 1) {
        acc[0] += __shfl_xor(acc[0], d, 64);
        acc[1] += __shfl_xor(acc[1], d, 64);
        acc[2] += __shfl_xor(acc[2], d, 64);
        acc[3] += __shfl_xor(acc[3], d, 64);
    }

    const float et = eta[0];
    const float hv0 = fast_tanh(acc[0] + bi[i0]);
    const float hv1 = fast_tanh(acc[1] + bi[i0 + 1]);
    const float hv2 = fast_tanh(acc[2] + bi[i0 + 2]);
    const float hv3 = fast_tanh(acc[3] + bi[i0 + 3]);

    if (lane == 0) {
        f4 hvv; hvv.x = hv0; hvv.y = hv1; hvv.z = hv2; hvv.w = hv3;
        *(f4*)(hidden + (size_t)b * HH + i0) = hvv;   // i0 % 4 == 0 -> aligned
    }

    const float e0 = et * hv0, e1 = et * hv1, e2 = et * hv2, e3 = et * hv3;

    *(f4*)(hebb_new + rbase + 0 * HH + j0) = clamp1(h0[0] + e0 * p0);
    *(f4*)(hebb_new + rbase + 0 * HH + j1) = clamp1(h1[0] + e0 * p1);
    *(f4*)(hebb_new + rbase + 1 * HH + j0) = clamp1(h0[1] + e1 * p0);
    *(f4*)(hebb_new + rbase + 1 * HH + j1) = clamp1(h1[1] + e1 * p1);
    *(f4*)(hebb_new + rbase + 2 * HH + j0) = clamp1(h0[2] + e2 * p0);
    *(f4*)(hebb_new + rbase + 2 * HH + j1) = clamp1(h1[2] + e2 * p1);
    *(f4*)(hebb_new + rbase + 3 * HH + j0) = clamp1(h0[3] + e3 * p0);
    *(f4*)(hebb_new + rbase + 3 * HH + j1) = clamp1(h1[3] + e3 * p1);
}

// One wave per output element: o in [0,256) -> a_out[b,o]; o==256 -> v_out[b].
__global__ __launch_bounds__(256) void out_proj_kernel(
    const float* __restrict__ hidden, const float* __restrict__ Wo,
    const float* __restrict__ bo,     const float* __restrict__ Wv,
    const float* __restrict__ bv,
    float* __restrict__ a_out, float* __restrict__ v_out)
{
    const int wid  = (blockIdx.x * 256 + threadIdx.x) >> 6;  // [0, 64*257)
    const int lane = threadIdx.x & 63;
    const int b = wid / 257;
    const int o = wid - b * 257;

    const int j0 = lane * 4;
    const int j1 = j0 + 256;

    const float* hrow = hidden + (size_t)b * HH;
    const f4 h0 = *(const f4*)(hrow + j0);
    const f4 h1 = *(const f4*)(hrow + j1);

    const float* wrow = (o < OUT_DIM) ? (Wo + (size_t)o * HH) : Wv;
    const f4 w0 = *(const f4*)(wrow + j0);
    const f4 w1 = *(const f4*)(wrow + j1);

    const f4 pv = h0 * w0 + h1 * w1;
    float acc = pv.x + pv.y + pv.z + pv.w;

    #pragma unroll
    for (int d = 32; d > 0; d >>= 1) acc += __shfl_xor(acc, d, 64);

    if (lane == 0) {
        if (o < OUT_DIM) a_out[(size_t)b * OUT_DIM + o] = acc + bo[o];
        else             v_out[b] = acc + bv[0];
    }
}

extern "C" void kernel_launch(void* const* d_in, const int* in_sizes, int n_in,
                              void* d_out, int out_size, void* d_ws, size_t ws_size,
                              hipStream_t stream) {
    const float* inputs = (const float*)d_in[0];
    const float* prev   = (const float*)d_in[1];
    const float* hebb   = (const float*)d_in[2];
    const float* w      = (const float*)d_in[3];
    const float* alpha  = (const float*)d_in[4];
    const float* eta    = (const float*)d_in[5];
    const float* Wi     = (const float*)d_in[6];
    const float* bi     = (const float*)d_in[7];
    const float* Wo     = (const float*)d_in[8];
    const float* bo     = (const float*)d_in[9];
    const float* Wv     = (const float*)d_in[10];
    const float* bv     = (const float*)d_in[11];

    float* out      = (float*)d_out;
    float* a_out    = out;                       // [B, OUT]
    float* v_out    = a_out + BB * OUT_DIM;      // [B, 1]
    float* hidden   = v_out + BB;                // [B, H]
    float* hebb_new = hidden + BB * HH;          // [B, H, H]

    // H/4 * B = 8192 waves, 4 per block -> 2048 blocks (multiple of 8)
    fused_row_kernel<<<dim3(HH / 4 * BB / 4), dim3(256), 0, stream>>>(
        inputs, prev, hebb, w, alpha, eta, Wi, bi, hidden, hebb_new);

    out_proj_kernel<<<dim3((BB * 257 + 3) / 4), dim3(256), 0, stream>>>(
        hidden, Wo, bo, Wv, bv, a_out, v_out);
}

// Round 17
// 30.287 us; speedup vs baseline: 1.7737x; 1.3813x over previous
//
#include <hip/hip_runtime.h>
#include <math.h>

#define BB 64
#define HH 512
#define IN_DIM 256
#define OUT_DIM 256

typedef float f4 __attribute__((ext_vector_type(4)));

__device__ __forceinline__ float fast_tanh(float x) {
    const float ax = fabsf(x);
    const float e  = __expf(2.f * ax);
    const float t  = 1.f - 2.f / (e + 1.f);
    return copysignf(t, x);
}

__device__ __forceinline__ f4 clamp1(f4 v) {
    return __builtin_elementwise_min(__builtin_elementwise_max(v, (f4)(-1.f)), (f4)(1.f));
}

// R12 configuration (best measured: 30.4 us).
// One wave handles FOUR rows (b, i0..i0+3) of hebb.
// i-slow / b-fast logical order + bijective XCD swizzle (grid 2048 = 8*256):
// XCD k executes logical blocks [256k, 256k+256) = 4 complete row-slabs, so
// each w/alpha slab is fetched into exactly one XCD's L2.
// __launch_bounds__(256, 4): natural ~52-VGPR body, no spills (R15/R16 showed
// tighter caps collapse the allocation and spill to scratch).
__global__ __launch_bounds__(256, 4) void fused_row_kernel(
    const float* __restrict__ inputs, const float* __restrict__ prev,
    const float* __restrict__ hebb,   const float* __restrict__ w,
    const float* __restrict__ alpha,  const float* __restrict__ eta,
    const float* __restrict__ Wi,     const float* __restrict__ bi,
    float* __restrict__ hidden, float* __restrict__ hebb_new)
{
    const int h   = blockIdx.x;
    const int cpx = gridDim.x >> 3;            // 256
    const int L   = (h & 7) * cpx + (h >> 3);  // bijective XCD swizzle

    const int wid4 = (L * 256 + (int)threadIdx.x) >> 6;  // [0, H/4*B)
    const int lane = threadIdx.x & 63;
    const int b  = wid4 & (BB - 1);      // batch fast
    const int i0 = (wid4 >> 6) * 4;      // row quad slow

    const int j0 = lane * 4;
    const int j1 = j0 + 256;

    const float* prow = prev + (size_t)b * HH;
    const f4 p0 = *(const f4*)(prow + j0);
    const f4 p1 = *(const f4*)(prow + j1);
    const f4 xv = *(const f4*)(inputs + (size_t)b * IN_DIM + j0);

    const size_t rbase = ((size_t)b * HH + i0) * HH;

    f4 h0[4], h1[4];
    #pragma unroll
    for (int r = 0; r < 4; ++r) {
        h0[r] = *(const f4*)(hebb + rbase + (size_t)r * HH + j0);
        h1[r] = *(const f4*)(hebb + rbase + (size_t)r * HH + j1);
    }

    float acc[4];
    #pragma unroll
    for (int r = 0; r < 4; ++r) {
        const size_t wo = (size_t)(i0 + r) * HH;
        const f4 w0 = *(const f4*)(w + wo + j0);
        const f4 w1 = *(const f4*)(w + wo + j1);
        const f4 a0 = *(const f4*)(alpha + wo + j0);
        const f4 a1 = *(const f4*)(alpha + wo + j1);
        f4 v = (w0 + a0 * h0[r]) * p0 + (w1 + a1 * h1[r]) * p1;
        const f4 wi = *(const f4*)(Wi + (size_t)(i0 + r) * IN_DIM + j0);
        v += wi * xv;
        acc[r] = v.x + v.y + v.z + v.w;
    }

    #pragma unroll
    for (int d = 32; d > 0; d >>= 1) {
        acc[0] += __shfl_xor(acc[0], d, 64);
        acc[1] += __shfl_xor(acc[1], d, 64);
        acc[2] += __shfl_xor(acc[2], d, 64);
        acc[3] += __shfl_xor(acc[3], d, 64);
    }

    const float et = eta[0];
    const float hv0 = fast_tanh(acc[0] + bi[i0]);
    const float hv1 = fast_tanh(acc[1] + bi[i0 + 1]);
    const float hv2 = fast_tanh(acc[2] + bi[i0 + 2]);
    const float hv3 = fast_tanh(acc[3] + bi[i0 + 3]);

    if (lane == 0) {
        f4 hvv; hvv.x = hv0; hvv.y = hv1; hvv.z = hv2; hvv.w = hv3;
        *(f4*)(hidden + (size_t)b * HH + i0) = hvv;   // i0 % 4 == 0 -> aligned
    }

    const float e0 = et * hv0, e1 = et * hv1, e2 = et * hv2, e3 = et * hv3;

    *(f4*)(hebb_new + rbase + 0 * HH + j0) = clamp1(h0[0] + e0 * p0);
    *(f4*)(hebb_new + rbase + 0 * HH + j1) = clamp1(h1[0] + e0 * p1);
    *(f4*)(hebb_new + rbase + 1 * HH + j0) = clamp1(h0[1] + e1 * p0);
    *(f4*)(hebb_new + rbase + 1 * HH + j1) = clamp1(h1[1] + e1 * p1);
    *(f4*)(hebb_new + rbase + 2 * HH + j0) = clamp1(h0[2] + e2 * p0);
    *(f4*)(hebb_new + rbase + 2 * HH + j1) = clamp1(h1[2] + e2 * p1);
    *(f4*)(hebb_new + rbase + 3 * HH + j0) = clamp1(h0[3] + e3 * p0);
    *(f4*)(hebb_new + rbase + 3 * HH + j1) = clamp1(h1[3] + e3 * p1);
}

// One wave per output element: o in [0,256) -> a_out[b,o]; o==256 -> v_out[b].
__global__ __launch_bounds__(256) void out_proj_kernel(
    const float* __restrict__ hidden, const float* __restrict__ Wo,
    const float* __restrict__ bo,     const float* __restrict__ Wv,
    const float* __restrict__ bv,
    float* __restrict__ a_out, float* __restrict__ v_out)
{
    const int wid  = (blockIdx.x * 256 + threadIdx.x) >> 6;  // [0, 64*257)
    const int lane = threadIdx.x & 63;
    const int b = wid / 257;
    const int o = wid - b * 257;

    const int j0 = lane * 4;
    const int j1 = j0 + 256;

    const float* hrow = hidden + (size_t)b * HH;
    const f4 h0 = *(const f4*)(hrow + j0);
    const f4 h1 = *(const f4*)(hrow + j1);

    const float* wrow = (o < OUT_DIM) ? (Wo + (size_t)o * HH) : Wv;
    const f4 w0 = *(const f4*)(wrow + j0);
    const f4 w1 = *(const f4*)(wrow + j1);

    const f4 pv = h0 * w0 + h1 * w1;
    float acc = pv.x + pv.y + pv.z + pv.w;

    #pragma unroll
    for (int d = 32; d > 0; d >>= 1) acc += __shfl_xor(acc, d, 64);

    if (lane == 0) {
        if (o < OUT_DIM) a_out[(size_t)b * OUT_DIM + o] = acc + bo[o];
        else             v_out[b] = acc + bv[0];
    }
}

extern "C" void kernel_launch(void* const* d_in, const int* in_sizes, int n_in,
                              void* d_out, int out_size, void* d_ws, size_t ws_size,
                              hipStream_t stream) {
    const float* inputs = (const float*)d_in[0];
    const float* prev   = (const float*)d_in[1];
    const float* hebb   = (const float*)d_in[2];
    const float* w      = (const float*)d_in[3];
    const float* alpha  = (const float*)d_in[4];
    const float* eta    = (const float*)d_in[5];
    const float* Wi     = (const float*)d_in[6];
    const float* bi     = (const float*)d_in[7];
    const float* Wo     = (const float*)d_in[8];
    const float* bo     = (const float*)d_in[9];
    const float* Wv     = (const float*)d_in[10];
    const float* bv     = (const float*)d_in[11];

    float* out      = (float*)d_out;
    float* a_out    = out;                       // [B, OUT]
    float* v_out    = a_out + BB * OUT_DIM;      // [B, 1]
    float* hidden   = v_out + BB;                // [B, H]
    float* hebb_new = hidden + BB * HH;          // [B, H, H]

    // H/4 * B = 8192 waves, 4 per block -> 2048 blocks (multiple of 8)
    fused_row_kernel<<<dim3(HH / 4 * BB / 4), dim3(256), 0, stream>>>(
        inputs, prev, hebb, w, alpha, eta, Wi, bi, hidden, hebb_new);

    out_proj_kernel<<<dim3((BB * 257 + 3) / 4), dim3(256), 0, stream>>>(
        hidden, Wo, bo, Wv, bv, a_out, v_out);
}